// Round 1
// baseline (595.802 us; speedup 1.0000x reference)
//
#include <hip/hip_runtime.h>
#include <hip/hip_bf16.h>
#include <cstdint>

// BahdanauAttention on MI355X — round 5: 256x256 8-phase counted-vmcnt GEMM.
// Fast path A (ws >= 132 MiB):
//   wt_k; conv_bf16_k; dec1_k; dec2_k (dp -> d_out ctx region);
//   gemm8_k (256^2 tile, BK=64, 8 waves, dbuf LDS 128K, raw s_barrier +
//            counted vmcnt(4)/vmcnt(2), setprio around MFMA clusters;
//            epilogue tanh+v-dot -> sp[4][M] partials);
//   softmax_part_k (sum 4 partials + mask + softmax -> attn);
//   ctx1_k (256-thr, s-split LDS reduce) ; ctx2_k.
// Path B/C: proven round-3 fallbacks (atomics + memsets), unchanged.

#define ENCD 1024
#define DECD 1024
#define BATCH 32
#define SEQ 2048
#define MTOT (BATCH * SEQ)  // 65536
#define KDIM 1024
#define NDIM 1024

typedef __attribute__((ext_vector_type(4))) float f32x4;
typedef __attribute__((ext_vector_type(8))) __bf16 bf16x8;
typedef __attribute__((ext_vector_type(8))) unsigned short u16x8;

__device__ __forceinline__ unsigned short f2bf(float f) {
  unsigned int u = __builtin_bit_cast(unsigned int, f);
  u += 0x7fffu + ((u >> 16) & 1u);  // RNE
  return (unsigned short)(u >> 16);
}

__device__ __forceinline__ float bf2f(unsigned short h) {
  return __builtin_bit_cast(float, (unsigned int)h << 16);
}

// async 16B/lane global->LDS DMA. LDS dest = wave-uniform base + lane*16.
__device__ __forceinline__ void async_lds16(const unsigned short* g, unsigned short* l) {
  __builtin_amdgcn_global_load_lds(
      (const __attribute__((address_space(1))) unsigned int*)g,
      (__attribute__((address_space(3))) unsigned int*)l, 16, 0, 0);
}

// raw barrier + compiler memory fence (keeps plain LDS ops inside their phase;
// does NOT emit the vmcnt(0) drain that __syncthreads carries).
__device__ __forceinline__ void barx() {
  __builtin_amdgcn_s_barrier();
  asm volatile("" ::: "memory");
}

template <int N>
__device__ __forceinline__ void waitv() {
  if constexpr (N == 0) {
    asm volatile("s_waitcnt vmcnt(0)" ::: "memory");
  } else if constexpr (N == 2) {
    asm volatile("s_waitcnt vmcnt(2)" ::: "memory");
  } else {
    asm volatile("s_waitcnt vmcnt(4)" ::: "memory");
  }
}

// ---------------- enc fp32 -> bf16 (one pass, memory-bound) ----------------
__global__ void conv_bf16_k(const float* __restrict__ src, unsigned short* __restrict__ dst) {
  const long i = ((long)blockIdx.x * 256 + threadIdx.x) * 8;
  const f32x4 f0 = *(const f32x4*)(src + i);
  const f32x4 f1 = *(const f32x4*)(src + i + 4);
  u16x8 v;
  v[0] = f2bf(f0[0]); v[1] = f2bf(f0[1]); v[2] = f2bf(f0[2]); v[3] = f2bf(f0[3]);
  v[4] = f2bf(f1[0]); v[5] = f2bf(f1[1]); v[6] = f2bf(f1[2]); v[7] = f2bf(f1[3]);
  *(u16x8*)(dst + i) = v;
}

// ---------------- W_enc transpose + bf16 convert: Wt[n][k] ----------------
__global__ void wt_k(const float* __restrict__ W, unsigned short* __restrict__ Wt) {
  __shared__ unsigned short t[64][65];
  const int k0 = blockIdx.x * 64, n0 = blockIdx.y * 64;
  const int tx = threadIdx.x & 63, ty = threadIdx.x >> 6;
#pragma unroll
  for (int i = 0; i < 16; ++i) {
    const int k = ty + i * 4;
    t[k][tx] = f2bf(W[(long)(DECD + k0 + k) * NDIM + n0 + tx]);
  }
  __syncthreads();
#pragma unroll
  for (int i = 0; i < 16; ++i) {
    const int n = ty + i * 4;
    Wt[(long)(n0 + n) * KDIM + k0 + tx] = t[tx][n];
  }
}

// ---------------- dec_proj fast: k-split partials, no atomics ----------------
__global__ void dec1_k(const float* __restrict__ dec, const float* __restrict__ W,
                       float* __restrict__ part) {
  const int idx = blockIdx.x * 256 + threadIdx.x;  // 32768 (b,n)
  const int kc = blockIdx.y;                       // 8 chunks of 128
  const int b = idx >> 10;
  const int n = idx & 1023;
  const float* d = dec + b * DECD + kc * 128;
  const float* w = W + (long)(kc * 128) * NDIM + n;
  float acc = 0.f;
#pragma unroll 8
  for (int k = 0; k < 128; ++k) acc = fmaf(d[k], w[(long)k * NDIM], acc);
  part[kc * 32768 + idx] = acc;
}

__global__ void dec2_k(const float* __restrict__ part, const float* __restrict__ bias,
                       float* __restrict__ dp) {
  const int idx = blockIdx.x * 256 + threadIdx.x;  // 32768
  float s = bias[idx & 1023];
#pragma unroll
  for (int kc = 0; kc < 8; ++kc) s += part[kc * 32768 + idx];
  dp[idx] = s;
}

// ================= 256x256 8-phase GEMM =================
// One K-tile (BK=64) = 4 phases. Per phase: frag ds_reads, 2 staging DMA,
// optional counted vmcnt, barrier, 16 MFMA (setprio-wrapped), barrier.
// Staging order per wave per tile t (for tile t+1, 8 issues):
//   P0: B rows [0..127] slice, P1: B rows [128..255] slice,
//   P2: A q0 (rows 0..63) + q2 (128..191), P3: A q1 (64..127) + q3 (192..255).
// Consumption: P0 of t+1 needs B(all) + A(q0,q2) = oldest 6  -> vmcnt(2) at end P3.
//              P2 of t+1 needs A(q1,q3); 4 newer issues exist -> vmcnt(4) at end P1.
template <bool STG, int W1, int W2>
__device__ __forceinline__ void gtile(
    const unsigned short* Acur, const unsigned short* Bcur,
    unsigned short* Anxt, unsigned short* Bnxt,
    const unsigned short* Ab, const unsigned short* Bb, int k0n,
    int wm, int wn, int wv, int quad, int l15, int srow, int schunk,
    f32x4 (&acc)[8][4], bf16x8 (&aF)[4][2], bf16x8 (&bF)[4][2]) {
  const int sw = l15 & 7;
#define RDF(buf, row, h) \
  __builtin_bit_cast(bf16x8, *(const u16x8*)&(buf)[(row) * 64 + ((((h) * 4 + quad) ^ sw) * 8)])
  // ---- P0: A(mh0) frags, B(nt0,1) frags; stage B rows 0..127 ----
#pragma unroll
  for (int mt = 0; mt < 4; ++mt) {
    const int row = wm * 128 + mt * 16 + l15;
    aF[mt][0] = RDF(Acur, row, 0);
    aF[mt][1] = RDF(Acur, row, 1);
  }
#pragma unroll
  for (int nt = 0; nt < 2; ++nt) {
    const int row = wn * 64 + nt * 16 + l15;
    bF[nt][0] = RDF(Bcur, row, 0);
    bF[nt][1] = RDF(Bcur, row, 1);
  }
  if (STG) {
    async_lds16(Bb + (size_t)(wv * 16 + srow) * KDIM + k0n + schunk * 8, Bnxt + (wv * 16) * 64);
    async_lds16(Bb + (size_t)(wv * 16 + 8 + srow) * KDIM + k0n + schunk * 8, Bnxt + (wv * 16 + 8) * 64);
  }
  barx();
  __builtin_amdgcn_s_setprio(1);
#pragma unroll
  for (int h = 0; h < 2; ++h)
#pragma unroll
    for (int mt = 0; mt < 4; ++mt)
#pragma unroll
      for (int nt = 0; nt < 2; ++nt)
        acc[mt][nt] = __builtin_amdgcn_mfma_f32_16x16x32_bf16(aF[mt][h], bF[nt][h], acc[mt][nt], 0, 0, 0);
  __builtin_amdgcn_s_setprio(0);
  barx();
  // ---- P1: B(nt2,3) frags; stage B rows 128..255; wait A(q1,q3) of cur ----
#pragma unroll
  for (int nt = 2; nt < 4; ++nt) {
    const int row = wn * 64 + nt * 16 + l15;
    bF[nt][0] = RDF(Bcur, row, 0);
    bF[nt][1] = RDF(Bcur, row, 1);
  }
  if (STG) {
    async_lds16(Bb + (size_t)(128 + wv * 16 + srow) * KDIM + k0n + schunk * 8, Bnxt + (128 + wv * 16) * 64);
    async_lds16(Bb + (size_t)(128 + wv * 16 + 8 + srow) * KDIM + k0n + schunk * 8, Bnxt + (128 + wv * 16 + 8) * 64);
  }
  waitv<W1>();
  barx();
  __builtin_amdgcn_s_setprio(1);
#pragma unroll
  for (int h = 0; h < 2; ++h)
#pragma unroll
    for (int mt = 0; mt < 4; ++mt)
#pragma unroll
      for (int nt = 0; nt < 2; ++nt)
        acc[mt][2 + nt] = __builtin_amdgcn_mfma_f32_16x16x32_bf16(aF[mt][h], bF[2 + nt][h], acc[mt][2 + nt], 0, 0, 0);
  __builtin_amdgcn_s_setprio(0);
  barx();
  // ---- P2: A(mh1) frags; stage A q0,q2 ----
#pragma unroll
  for (int mt = 0; mt < 4; ++mt) {
    const int row = wm * 128 + (4 + mt) * 16 + l15;
    aF[mt][0] = RDF(Acur, row, 0);
    aF[mt][1] = RDF(Acur, row, 1);
  }
  if (STG) {
    async_lds16(Ab + (size_t)(wv * 8 + srow) * KDIM + k0n + schunk * 8, Anxt + (wv * 8) * 64);
    async_lds16(Ab + (size_t)(128 + wv * 8 + srow) * KDIM + k0n + schunk * 8, Anxt + (128 + wv * 8) * 64);
  }
  barx();
  __builtin_amdgcn_s_setprio(1);
#pragma unroll
  for (int h = 0; h < 2; ++h)
#pragma unroll
    for (int mt = 0; mt < 4; ++mt)
#pragma unroll
      for (int nt = 0; nt < 2; ++nt)
        acc[4 + mt][nt] = __builtin_amdgcn_mfma_f32_16x16x32_bf16(aF[mt][h], bF[nt][h], acc[4 + mt][nt], 0, 0, 0);
  __builtin_amdgcn_s_setprio(0);
  barx();
  // ---- P3: stage A q1,q3; wait next-tile B(all)+A(q0,q2) ----
  if (STG) {
    async_lds16(Ab + (size_t)(64 + wv * 8 + srow) * KDIM + k0n + schunk * 8, Anxt + (64 + wv * 8) * 64);
    async_lds16(Ab + (size_t)(192 + wv * 8 + srow) * KDIM + k0n + schunk * 8, Anxt + (192 + wv * 8) * 64);
  }
  waitv<W2>();
  barx();
  __builtin_amdgcn_s_setprio(1);
#pragma unroll
  for (int h = 0; h < 2; ++h)
#pragma unroll
    for (int mt = 0; mt < 4; ++mt)
#pragma unroll
      for (int nt = 0; nt < 2; ++nt)
        acc[4 + mt][2 + nt] = __builtin_amdgcn_mfma_f32_16x16x32_bf16(aF[mt][h], bF[2 + nt][h], acc[4 + mt][2 + nt], 0, 0, 0);
  __builtin_amdgcn_s_setprio(0);
  barx();
#undef RDF
}

__global__ __launch_bounds__(512, 2) void gemm8_k(
    const unsigned short* __restrict__ Abf, const unsigned short* __restrict__ Wt,
    const float* __restrict__ dp, const float* __restrict__ vw,
    float* __restrict__ sp) {
  __shared__ unsigned short sA[2][256 * 64];  // 64 KiB
  __shared__ unsigned short sB[2][256 * 64];  // 64 KiB
  const int tid = threadIdx.x;
  const int lane = tid & 63;
  const int wv = tid >> 6;            // 0..7
  const int wm = wv >> 2, wn = wv & 3;
  const int quad = lane >> 4;
  const int l15 = lane & 15;
  const int srow = lane >> 3;
  const int schunk = (lane & 7) ^ srow;

  const int bn = blockIdx.x;          // 0..3
  const int bm = blockIdx.y;          // 0..255
  const int n0 = bn * 256;
  const int row0 = bm * 256;
  const int bidx = bm >> 3;           // 256 rows per block, 2048 per batch

  const unsigned short* Ab = Abf + (size_t)row0 * KDIM;
  const unsigned short* Bb = Wt + (size_t)n0 * KDIM;

  const f32x4 zz = {0.f, 0.f, 0.f, 0.f};
  f32x4 acc[8][4];
#pragma unroll
  for (int i = 0; i < 8; ++i)
#pragma unroll
    for (int j = 0; j < 4; ++j) acc[i][j] = zz;
  bf16x8 aF[4][2], bF[4][2];

  // prologue: stage tile 0 into buffer 0. Order: B(4), A q0,q2, A q1,q3.
  async_lds16(Bb + (size_t)(wv * 16 + srow) * KDIM + schunk * 8, &sB[0][(wv * 16) * 64]);
  async_lds16(Bb + (size_t)(wv * 16 + 8 + srow) * KDIM + schunk * 8, &sB[0][(wv * 16 + 8) * 64]);
  async_lds16(Bb + (size_t)(128 + wv * 16 + srow) * KDIM + schunk * 8, &sB[0][(128 + wv * 16) * 64]);
  async_lds16(Bb + (size_t)(128 + wv * 16 + 8 + srow) * KDIM + schunk * 8, &sB[0][(128 + wv * 16 + 8) * 64]);
  async_lds16(Ab + (size_t)(wv * 8 + srow) * KDIM + schunk * 8, &sA[0][(wv * 8) * 64]);
  async_lds16(Ab + (size_t)(128 + wv * 8 + srow) * KDIM + schunk * 8, &sA[0][(128 + wv * 8) * 64]);
  async_lds16(Ab + (size_t)(64 + wv * 8 + srow) * KDIM + schunk * 8, &sA[0][(64 + wv * 8) * 64]);
  async_lds16(Ab + (size_t)(192 + wv * 8 + srow) * KDIM + schunk * 8, &sA[0][(192 + wv * 8) * 64]);
  waitv<2>();
  barx();

  // 16 K-tiles: 7 double-iterations + final pair (last tile stages nothing).
  for (int it = 0; it < 7; ++it) {
    const int kb = it * 2;
    gtile<true, 4, 2>(sA[0], sB[0], sA[1], sB[1], Ab, Bb, (kb + 1) * 64,
                      wm, wn, wv, quad, l15, srow, schunk, acc, aF, bF);
    gtile<true, 4, 2>(sA[1], sB[1], sA[0], sB[0], Ab, Bb, (kb + 2) * 64,
                      wm, wn, wv, quad, l15, srow, schunk, acc, aF, bF);
  }
  gtile<true, 4, 2>(sA[0], sB[0], sA[1], sB[1], Ab, Bb, 15 * 64,
                    wm, wn, wv, quad, l15, srow, schunk, acc, aF, bF);
  gtile<false, 0, 0>(sA[1], sB[1], sA[0], sB[0], Ab, Bb, 0,
                     wm, wn, wv, quad, l15, srow, schunk, acc, aF, bF);

  // Epilogue: per-row tanh/v-dot partial over this block's 256 n-columns.
  float vv[4], dv[4];
#pragma unroll
  for (int nt = 0; nt < 4; ++nt) {
    const int n = n0 + wn * 64 + nt * 16 + l15;
    vv[nt] = vw[n];
    dv[nt] = dp[bidx * NDIM + n];  // bias already folded in
  }
  float* sRed = (float*)sA;  // [4][256] floats; all LDS reads done (final barrier)
#pragma unroll
  for (int mt = 0; mt < 8; ++mt) {
#pragma unroll
    for (int r = 0; r < 4; ++r) {
      float s = 0.f;
#pragma unroll
      for (int nt = 0; nt < 4; ++nt) {
        float x = acc[mt][nt][r] + dv[nt];
        x = fminf(fmaxf(x, -10.f), 10.f);
        const float e = __expf(2.f * x);
        s += (e - 1.f) * __builtin_amdgcn_rcpf(e + 1.f) * vv[nt];  // tanh
      }
      s += __shfl_xor(s, 1);
      s += __shfl_xor(s, 2);
      s += __shfl_xor(s, 4);
      s += __shfl_xor(s, 8);
      if (l15 == 0) sRed[wn * 256 + wm * 128 + mt * 16 + quad * 4 + r] = s;
    }
  }
  __syncthreads();
  if (tid < 256) {
    const float s4 = sRed[tid] + sRed[256 + tid] + sRed[512 + tid] + sRed[768 + tid];
    sp[(size_t)bn * MTOT + row0 + tid] = s4;
  }
}

// ---------------- softmax over summed partials -> attn ----------------
__global__ void softmax_part_k(const float* __restrict__ sp, const int* __restrict__ mask,
                               float* __restrict__ attn) {
  const int b = blockIdx.x;
  const int tid = threadIdx.x;
  const int w = tid >> 6;
  __shared__ float redm[4], reds[4];
  const int* mrow = mask + b * SEQ;
  float vals[8];
  float mx = -3.0e38f;
#pragma unroll
  for (int i = 0; i < 8; ++i) {
    const int s = tid + i * 256;
    float v = 0.f;
#pragma unroll
    for (int bn = 0; bn < 4; ++bn) v += sp[(size_t)bn * MTOT + b * SEQ + s];
    if (mrow[s] == 0) v = -1.0e9f;
    vals[i] = v;
    mx = fmaxf(mx, v);
  }
#pragma unroll
  for (int off = 1; off < 64; off <<= 1) mx = fmaxf(mx, __shfl_xor(mx, off));
  if ((tid & 63) == 0) redm[w] = mx;
  __syncthreads();
  mx = fmaxf(fmaxf(redm[0], redm[1]), fmaxf(redm[2], redm[3]));
  float sum = 0.f;
#pragma unroll
  for (int i = 0; i < 8; ++i) {
    vals[i] = __expf(vals[i] - mx);
    sum += vals[i];
  }
#pragma unroll
  for (int off = 1; off < 64; off <<= 1) sum += __shfl_xor(sum, off);
  if ((tid & 63) == 0) reds[w] = sum;
  __syncthreads();
  sum = reds[0] + reds[1] + reds[2] + reds[3];
  const float inv = 1.0f / sum;
#pragma unroll
  for (int i = 0; i < 8; ++i) attn[b * SEQ + tid + i * 256] = vals[i] * inv;
}

// ---------------- context stage 1: bf16 enc, s-chunk partials ----------------
// 256 threads: tid>>7 picks an s-half (64 rows), in-block LDS reduce.
__global__ void ctx1_k(const float* __restrict__ attn, const unsigned short* __restrict__ Abf,
                       float* __restrict__ part) {
  __shared__ float red[128 * 8];
  const int sc = blockIdx.x;  // 16 chunks of 128 s
  const int b = blockIdx.y;   // 32
  const int half = threadIdx.x >> 7;
  const int te = threadIdx.x & 127;
  const int e0 = te * 8;
  const int sbase = sc * 128 + half * 64;
  const float* arow = attn + b * SEQ + sbase;
  const unsigned short* base = Abf + (size_t)(b * SEQ + sbase) * ENCD + e0;
  float acc[8] = {0.f, 0.f, 0.f, 0.f, 0.f, 0.f, 0.f, 0.f};
#pragma unroll 8
  for (int s = 0; s < 64; ++s) {
    const float w = arow[s];
    const u16x8 v = *(const u16x8*)(base + (size_t)s * ENCD);
#pragma unroll
    for (int j = 0; j < 8; ++j) acc[j] = fmaf(w, bf2f(v[j]), acc[j]);
  }
  if (half == 1) {
#pragma unroll
    for (int j = 0; j < 8; ++j) red[te * 8 + j] = acc[j];
  }
  __syncthreads();
  if (half == 0) {
#pragma unroll
    for (int j = 0; j < 8; ++j) acc[j] += red[te * 8 + j];
    float* dst = part + (size_t)sc * (BATCH * ENCD) + b * ENCD + e0;
    *(f32x4*)dst = *(f32x4*)&acc[0];
    *(f32x4*)(dst + 4) = *(f32x4*)&acc[4];
  }
}

__global__ void ctx2_k(const float* __restrict__ part, float* __restrict__ ctx) {
  const int i = blockIdx.x * 256 + threadIdx.x;  // 32768
  float s = 0.f;
#pragma unroll
  for (int c = 0; c < 16; ++c) s += part[(size_t)c * (BATCH * ENCD) + i];
  ctx[i] = s;
}

// ================= Path B/C fallback kernels (round-3 proven) =================
__global__ void dec_proj_k2(const float* __restrict__ dec, const float* __restrict__ W,
                            float* __restrict__ dp) {
  const int idx = blockIdx.x * 256 + threadIdx.x;
  const int kc = blockIdx.y;
  const int b = idx >> 10;
  const int n = idx & 1023;
  const float* d = dec + b * DECD + kc * 128;
  const float* w = W + (long)(kc * 128) * NDIM + n;
  float acc = 0.f;
#pragma unroll 8
  for (int k = 0; k < 128; ++k) acc = fmaf(d[k], w[(long)k * NDIM], acc);
  atomicAdd(&dp[idx], acc);
}

__global__ __launch_bounds__(256, 3) void gemm_scores_bf16(
    const unsigned short* __restrict__ Abf, const unsigned short* __restrict__ Wt,
    const float* __restrict__ dp, const float* __restrict__ bias,
    const float* __restrict__ vw, float* __restrict__ scores) {
  __shared__ unsigned short sA[128 * 64];
  __shared__ unsigned short sB[128 * 64];
  const int tid = threadIdx.x;
  const int lane = tid & 63;
  const int wave = tid >> 6;
  const int wm = wave >> 1, wn = wave & 1;
  const int quad = lane >> 4;
  const int l15 = lane & 15;
  const int bn = blockIdx.x, bm = blockIdx.y;
  const int n0 = bn * 128, row0 = bm * 128, bidx = bm >> 4;
  const int srow = lane >> 3;
  const int schunk = (lane & 7) ^ srow;
  const f32x4 zz = {0.f, 0.f, 0.f, 0.f};
  f32x4 acc[4][4];
#pragma unroll
  for (int i = 0; i < 4; ++i)
#pragma unroll
    for (int j = 0; j < 4; ++j) acc[i][j] = zz;
  for (int kt = 0; kt < 16; ++kt) {
    const int k0 = kt * 64;
    __syncthreads();
#pragma unroll
    for (int i = 0; i < 4; ++i) {
      const int r = wave * 32 + i * 8 + srow;
      async_lds16(Abf + (size_t)(row0 + r) * KDIM + k0 + schunk * 8,
                  &sA[(wave * 32 + i * 8) * 64]);
      async_lds16(Wt + (size_t)(n0 + r) * KDIM + k0 + schunk * 8,
                  &sB[(wave * 32 + i * 8) * 64]);
    }
    __syncthreads();
#pragma unroll
    for (int h = 0; h < 2; ++h) {
      bf16x8 af[4], bf[4];
      const int slot = ((h * 4 + quad) ^ (l15 & 7)) * 8;
#pragma unroll
      for (int t = 0; t < 4; ++t) {
        af[t] = __builtin_bit_cast(bf16x8, *(const u16x8*)&sA[(wm * 64 + t * 16 + l15) * 64 + slot]);
        bf[t] = __builtin_bit_cast(bf16x8, *(const u16x8*)&sB[(wn * 64 + t * 16 + l15) * 64 + slot]);
      }
#pragma unroll
      for (int mt = 0; mt < 4; ++mt)
#pragma unroll
        for (int nt = 0; nt < 4; ++nt)
          acc[mt][nt] = __builtin_amdgcn_mfma_f32_16x16x32_bf16(
              af[mt], bf[nt], acc[mt][nt], 0, 0, 0);
    }
  }
  float vv[4], dv[4];
#pragma unroll
  for (int nt = 0; nt < 4; ++nt) {
    const int n = n0 + wn * 64 + nt * 16 + l15;
    vv[nt] = vw[n];
    dv[nt] = dp[bidx * NDIM + n] + bias[n];
  }
#pragma unroll
  for (int mt = 0; mt < 4; ++mt) {
#pragma unroll
    for (int r = 0; r < 4; ++r) {
      float s = 0.f;
#pragma unroll
      for (int nt = 0; nt < 4; ++nt) {
        float x = acc[mt][nt][r] + dv[nt];
        x = fminf(fmaxf(x, -10.f), 10.f);
        const float e = __expf(2.f * x);
        s += (e - 1.f) * __builtin_amdgcn_rcpf(e + 1.f) * vv[nt];
      }
      s += __shfl_xor(s, 1);
      s += __shfl_xor(s, 2);
      s += __shfl_xor(s, 4);
      s += __shfl_xor(s, 8);
      if (l15 == 0) atomicAdd(&scores[row0 + wm * 64 + mt * 16 + quad * 4 + r], s);
    }
  }
}

__global__ __launch_bounds__(256, 2) void gemm_scores_f32(
    const float* __restrict__ Ag, const unsigned short* __restrict__ Wt,
    const float* __restrict__ dp, const float* __restrict__ bias,
    const float* __restrict__ vw, float* __restrict__ scores) {
  __shared__ unsigned short sA[128 * 64];
  __shared__ unsigned short sB[128 * 64];
  const int tid = threadIdx.x;
  const int lane = tid & 63;
  const int wave = tid >> 6;
  const int wm = wave >> 1, wn = wave & 1;
  const int quad = lane >> 4;
  const int l15 = lane & 15;
  const int bn = blockIdx.x, bm = blockIdx.y;
  const int n0 = bn * 128, row0 = bm * 128, bidx = bm >> 4;
  const int sr = tid >> 3, sc = tid & 7;
  const f32x4 zz = {0.f, 0.f, 0.f, 0.f};
  f32x4 acc[4][4];
#pragma unroll
  for (int i = 0; i < 4; ++i)
#pragma unroll
    for (int j = 0; j < 4; ++j) acc[i][j] = zz;
  for (int kt = 0; kt < 16; ++kt) {
    const int k0 = kt * 64;
    __syncthreads();
#pragma unroll
    for (int j = 0; j < 4; ++j) {
      const int r = sr + 32 * j;
      const int c = sc ^ (r & 7);
      const float* src = Ag + (long)(row0 + r) * KDIM + (k0 + c * 8);
      f32x4 f0 = *(const f32x4*)src;
      f32x4 f1 = *(const f32x4*)(src + 4);
      u16x8 v;
      v[0] = f2bf(f0[0]); v[1] = f2bf(f0[1]); v[2] = f2bf(f0[2]); v[3] = f2bf(f0[3]);
      v[4] = f2bf(f1[0]); v[5] = f2bf(f1[1]); v[6] = f2bf(f1[2]); v[7] = f2bf(f1[3]);
      *(u16x8*)&sA[r * 64 + sc * 8] = v;
      *(u16x8*)&sB[r * 64 + sc * 8] = *(const u16x8*)(Wt + (long)(n0 + r) * KDIM + (k0 + c * 8));
    }
    __syncthreads();
#pragma unroll
    for (int h = 0; h < 2; ++h) {
      const int cs = ((h * 4 + quad) ^ (lane & 7)) * 8;
      bf16x8 af[4], bf[4];
#pragma unroll
      for (int t = 0; t < 4; ++t) {
        af[t] = __builtin_bit_cast(bf16x8, *(const u16x8*)&sA[(wm * 64 + t * 16 + l15) * 64 + cs]);
        bf[t] = __builtin_bit_cast(bf16x8, *(const u16x8*)&sB[(wn * 64 + t * 16 + l15) * 64 + cs]);
      }
#pragma unroll
      for (int mt = 0; mt < 4; ++mt)
#pragma unroll
        for (int nt = 0; nt < 4; ++nt)
          acc[mt][nt] = __builtin_amdgcn_mfma_f32_16x16x32_bf16(
              af[mt], bf[nt], acc[mt][nt], 0, 0, 0);
    }
  }
  float vv[4], dv[4];
#pragma unroll
  for (int nt = 0; nt < 4; ++nt) {
    const int n = n0 + wn * 64 + nt * 16 + l15;
    vv[nt] = vw[n];
    dv[nt] = dp[bidx * NDIM + n] + bias[n];
  }
#pragma unroll
  for (int mt = 0; mt < 4; ++mt) {
#pragma unroll
    for (int r = 0; r < 4; ++r) {
      float s = 0.f;
#pragma unroll
      for (int nt = 0; nt < 4; ++nt) {
        float x = acc[mt][nt][r] + dv[nt];
        x = fminf(fmaxf(x, -10.f), 10.f);
        const float e = __expf(2.f * x);
        s += (e - 1.f) * __builtin_amdgcn_rcpf(e + 1.f) * vv[nt];
      }
      s += __shfl_xor(s, 1);
      s += __shfl_xor(s, 2);
      s += __shfl_xor(s, 4);
      s += __shfl_xor(s, 8);
      if (l15 == 0) atomicAdd(&scores[row0 + wm * 64 + mt * 16 + quad * 4 + r], s);
    }
  }
}

__global__ void softmax_k(float* __restrict__ sc, const int* __restrict__ mask) {
  const int b = blockIdx.x;
  const int tid = threadIdx.x;
  const int w = tid >> 6;
  __shared__ float redm[4], reds[4];
  float* row = sc + b * SEQ;
  const int* mrow = mask + b * SEQ;
  float vals[8];
  float mx = -3.0e38f;
#pragma unroll
  for (int i = 0; i < 8; ++i) {
    const int s = tid + i * 256;
    float v = row[s];
    if (mrow[s] == 0) v = -1.0e9f;
    vals[i] = v;
    mx = fmaxf(mx, v);
  }
#pragma unroll
  for (int off = 1; off < 64; off <<= 1) mx = fmaxf(mx, __shfl_xor(mx, off));
  if ((tid & 63) == 0) redm[w] = mx;
  __syncthreads();
  mx = fmaxf(fmaxf(redm[0], redm[1]), fmaxf(redm[2], redm[3]));
  float sum = 0.f;
#pragma unroll
  for (int i = 0; i < 8; ++i) {
    vals[i] = __expf(vals[i] - mx);
    sum += vals[i];
  }
#pragma unroll
  for (int off = 1; off < 64; off <<= 1) sum += __shfl_xor(sum, off);
  if ((tid & 63) == 0) reds[w] = sum;
  __syncthreads();
  sum = reds[0] + reds[1] + reds[2] + reds[3];
  const float inv = 1.0f / sum;
#pragma unroll
  for (int i = 0; i < 8; ++i) row[tid + i * 256] = vals[i] * inv;
}

__global__ void context_k(const float* __restrict__ attn, const float* __restrict__ enc,
                          float* __restrict__ ctx) {
  const int b = blockIdx.y;
  const int s0 = blockIdx.x * 32;
  const int e = threadIdx.x * 4;
  const float* arow = attn + b * SEQ + s0;
  const float* ebase = enc + (long)(b * SEQ + s0) * ENCD + e;
  f32x4 acc = {0.f, 0.f, 0.f, 0.f};
#pragma unroll 8
  for (int s = 0; s < 32; ++s) {
    const float w = arow[s];
    const f32x4 v = *(const f32x4*)(ebase + (long)s * ENCD);
    acc += w * v;
  }
  float* dst = ctx + b * ENCD + e;
  atomicAdd(dst + 0, acc[0]);
  atomicAdd(dst + 1, acc[1]);
  atomicAdd(dst + 2, acc[2]);
  atomicAdd(dst + 3, acc[3]);
}

extern "C" void kernel_launch(void* const* d_in, const int* in_sizes, int n_in,
                              void* d_out, int out_size, void* d_ws, size_t ws_size,
                              hipStream_t stream) {
  (void)in_sizes; (void)n_in; (void)out_size;
  const float* dec  = (const float*)d_in[0];
  const float* enc  = (const float*)d_in[1];
  const int*   mask = (const int*)d_in[2];
  const float* W    = (const float*)d_in[3];
  const float* bias = (const float*)d_in[4];
  const float* vw   = (const float*)d_in[5];

  float* ctx  = (float*)d_out;                 // context region (also dp parking)
  float* attn = (float*)d_out + BATCH * ENCD;  // attn region (scores in-place for B/C)
  unsigned short* Wt  = (unsigned short*)d_ws;                         // 2 MiB
  unsigned short* Abf = (unsigned short*)((char*)d_ws + (2ull << 20)); // 128 MiB
  float* shared = (float*)((char*)d_ws + (130ull << 20));              // 2 MiB multi-use

  const size_t needA = (132ull << 20);
  const size_t needB = (2ull << 20) + ((size_t)MTOT * KDIM * 2);

  wt_k<<<dim3(16, 16), 256, 0, stream>>>(W, Wt);
  if (ws_size >= needA) {
    // dp_part -> shared (1 MiB), then dp -> ctx region
    dec1_k<<<dim3(128, 8), 256, 0, stream>>>(dec, W, shared);
    dec2_k<<<128, 256, 0, stream>>>(shared, bias, ctx);
    conv_bf16_k<<<32768, 256, 0, stream>>>(enc, Abf);
    // score partials sp[4][65536] -> shared (1 MiB)
    gemm8_k<<<dim3(4, 256), 512, 0, stream>>>(Abf, Wt, ctx, vw, shared);
    softmax_part_k<<<32, 256, 0, stream>>>(shared, mask, attn);
    // ctx partials [16][32768] -> shared (2 MiB)
    ctx1_k<<<dim3(16, 32), 256, 0, stream>>>(attn, Abf, shared);
    ctx2_k<<<128, 256, 0, stream>>>(shared, ctx);
  } else if (ws_size >= needB) {
    hipMemsetAsync(attn, 0, (size_t)MTOT * sizeof(float), stream);
    hipMemsetAsync(ctx, 0, (size_t)(BATCH * NDIM) * sizeof(float), stream);
    dec_proj_k2<<<dim3(128, 8), 256, 0, stream>>>(dec, W, ctx);
    conv_bf16_k<<<32768, 256, 0, stream>>>(enc, Abf);
    gemm_scores_bf16<<<dim3(8, 512), 256, 0, stream>>>(Abf, Wt, ctx, bias, vw, attn);
    softmax_k<<<32, 256, 0, stream>>>(attn, mask);
    hipMemsetAsync(ctx, 0, (size_t)(BATCH * ENCD) * sizeof(float), stream);
    context_k<<<dim3(64, 32), 256, 0, stream>>>(attn, enc, ctx);
  } else {
    hipMemsetAsync(attn, 0, (size_t)MTOT * sizeof(float), stream);
    hipMemsetAsync(ctx, 0, (size_t)(BATCH * NDIM) * sizeof(float), stream);
    dec_proj_k2<<<dim3(128, 8), 256, 0, stream>>>(dec, W, ctx);
    gemm_scores_f32<<<dim3(8, 512), 256, 0, stream>>>(enc, Wt, ctx, bias, vw, attn);
    softmax_k<<<32, 256, 0, stream>>>(attn, mask);
    hipMemsetAsync(ctx, 0, (size_t)(BATCH * ENCD) * sizeof(float), stream);
    context_k<<<dim3(64, 32), 256, 0, stream>>>(attn, enc, ctx);
  }
}

// Round 2
// 584.543 us; speedup vs baseline: 1.0193x; 1.0193x over previous
//
#include <hip/hip_runtime.h>
#include <hip/hip_bf16.h>
#include <cstdint>

// BahdanauAttention on MI355X — round 6:
// Path A (ws >= 132 MiB), 3 dispatches:
//   prep_k   : fused {dec_proj full-K -> dp(ctx region)} | {W_enc^T -> bf16 Wt} | {enc fp32->bf16 Abf}
//   gemm8_k  : 256^2 8-phase GEMM v2 — stage tile t+2 during tile t (B in P2, A in P3),
//              ONE vmcnt(8) per K-tile (never drains below 8 in flight),
//              bijective XCD swizzle grouping the 4 bn-siblings per A-panel,
//              epilogue tanh+v-dot -> sp[4][M] partials.
//   sm_ctx_k : per-(b,echunk) block: softmax from sp partials (redundant, in-LDS),
//              attn written by ec==0, context reduction in-block -> ctx.
// Path B/C: proven round-3 fallbacks (atomics + memsets), unchanged.

#define ENCD 1024
#define DECD 1024
#define BATCH 32
#define SEQ 2048
#define MTOT (BATCH * SEQ)  // 65536
#define KDIM 1024
#define NDIM 1024

typedef __attribute__((ext_vector_type(4))) float f32x4;
typedef __attribute__((ext_vector_type(8))) __bf16 bf16x8;
typedef __attribute__((ext_vector_type(8))) unsigned short u16x8;

__device__ __forceinline__ unsigned short f2bf(float f) {
  unsigned int u = __builtin_bit_cast(unsigned int, f);
  u += 0x7fffu + ((u >> 16) & 1u);  // RNE
  return (unsigned short)(u >> 16);
}

__device__ __forceinline__ float bf2f(unsigned short h) {
  return __builtin_bit_cast(float, (unsigned int)h << 16);
}

// async 16B/lane global->LDS DMA. LDS dest = wave-uniform base + lane*16.
__device__ __forceinline__ void async_lds16(const unsigned short* g, unsigned short* l) {
  __builtin_amdgcn_global_load_lds(
      (const __attribute__((address_space(1))) unsigned int*)g,
      (__attribute__((address_space(3))) unsigned int*)l, 16, 0, 0);
}

// raw barrier + compiler memory fence (no vmcnt(0) drain like __syncthreads).
__device__ __forceinline__ void barx() {
  __builtin_amdgcn_s_barrier();
  asm volatile("" ::: "memory");
}

template <int N>
__device__ __forceinline__ void waitv() {
  if constexpr (N == 0) {
    asm volatile("s_waitcnt vmcnt(0)" ::: "memory");
  } else {
    asm volatile("s_waitcnt vmcnt(8)" ::: "memory");
  }
}

// ---------------- standalone helpers (used by fallback paths) ----------------
__global__ void conv_bf16_k(const float* __restrict__ src, unsigned short* __restrict__ dst) {
  const long i = ((long)blockIdx.x * 256 + threadIdx.x) * 8;
  const f32x4 f0 = *(const f32x4*)(src + i);
  const f32x4 f1 = *(const f32x4*)(src + i + 4);
  u16x8 v;
  v[0] = f2bf(f0[0]); v[1] = f2bf(f0[1]); v[2] = f2bf(f0[2]); v[3] = f2bf(f0[3]);
  v[4] = f2bf(f1[0]); v[5] = f2bf(f1[1]); v[6] = f2bf(f1[2]); v[7] = f2bf(f1[3]);
  *(u16x8*)(dst + i) = v;
}

__global__ void wt_k(const float* __restrict__ W, unsigned short* __restrict__ Wt) {
  __shared__ unsigned short t[64][65];
  const int k0 = blockIdx.x * 64, n0 = blockIdx.y * 64;
  const int tx = threadIdx.x & 63, ty = threadIdx.x >> 6;
#pragma unroll
  for (int i = 0; i < 16; ++i) {
    const int k = ty + i * 4;
    t[k][tx] = f2bf(W[(long)(DECD + k0 + k) * NDIM + n0 + tx]);
  }
  __syncthreads();
#pragma unroll
  for (int i = 0; i < 16; ++i) {
    const int n = ty + i * 4;
    Wt[(long)(n0 + n) * KDIM + k0 + tx] = t[tx][n];
  }
}

// ---------------- fused prep: dec_proj | W^T | conv, branch on blockIdx ----------------
__global__ __launch_bounds__(256) void prep_k(
    const float* __restrict__ dec, const float* __restrict__ enc,
    const float* __restrict__ W, const float* __restrict__ bias,
    float* __restrict__ dp, unsigned short* __restrict__ Wt,
    unsigned short* __restrict__ Abf) {
  const int gb = blockIdx.x;
  const int tid = threadIdx.x;
  if (gb < 128) {
    // dec_proj full-K: block = (b, n-chunk of 256); coalesced W rows.
    const int b = gb >> 2;
    const int n = (gb & 3) * 256 + tid;
    const float* d = dec + b * DECD;
    const float* w = W + n;
    float acc = bias[n];
#pragma unroll 8
    for (int k = 0; k < 1024; ++k) acc = fmaf(d[k], w[(size_t)k * NDIM], acc);
    dp[b * NDIM + n] = acc;
  } else if (gb < 384) {
    // W_enc transpose + bf16 convert: Wt[n][k]
    __shared__ unsigned short t[64][65];
    const int g2 = gb - 128;
    const int k0 = (g2 & 15) * 64, n0 = (g2 >> 4) * 64;
    const int tx = tid & 63, ty = tid >> 6;
#pragma unroll
    for (int i = 0; i < 16; ++i) {
      const int k = ty + i * 4;
      t[k][tx] = f2bf(W[(size_t)(DECD + k0 + k) * NDIM + n0 + tx]);
    }
    __syncthreads();
#pragma unroll
    for (int i = 0; i < 16; ++i) {
      const int n = ty + i * 4;
      Wt[(size_t)(n0 + n) * KDIM + k0 + tx] = t[tx][n];
    }
  } else {
    // enc fp32 -> bf16, one pass
    const long i = ((long)(gb - 384) * 256 + tid) * 8;
    const f32x4 f0 = *(const f32x4*)(enc + i);
    const f32x4 f1 = *(const f32x4*)(enc + i + 4);
    u16x8 v;
    v[0] = f2bf(f0[0]); v[1] = f2bf(f0[1]); v[2] = f2bf(f0[2]); v[3] = f2bf(f0[3]);
    v[4] = f2bf(f1[0]); v[5] = f2bf(f1[1]); v[6] = f2bf(f1[2]); v[7] = f2bf(f1[3]);
    *(u16x8*)(Abf + i) = v;
  }
}

// ================= 256x256 8-phase GEMM v2 =================
// Tile t reads sA/sB[t&1]; tile t+2 is staged INTO the same parity buffer:
//   B_{t+2} issued in P2 (B[t&1] fully read by end-P1),
//   A_{t+2} issued in P3 (A[t&1] fully read by end-P2).
// ONE wait per tile, end of P3: vmcnt(8) -> completes all 8 loads of tile t+1
// (issued 5-6 phases earlier) while 8 loads of t+2 stay in flight.

// stages one 256x64 operand tile (4 DMA calls, 8 rows/wave each)
__device__ __forceinline__ void stage4(const unsigned short* gbase, unsigned short* lbase,
                                       int wv, int srow, int schunk, int k0) {
#pragma unroll
  for (int j = 0; j < 4; ++j) {
    async_lds16(gbase + (size_t)(j * 64 + wv * 8 + srow) * KDIM + k0 + schunk * 8,
                lbase + (j * 64 + wv * 8) * 64);
  }
}

template <bool STG, int BW>
__device__ __forceinline__ void gtile2(
    unsigned short* sAc, unsigned short* sBc,
    const unsigned short* Ab, const unsigned short* Bb, int k2,
    int wm, int wn, int wv, int quad, int l15, int srow, int schunk,
    f32x4 (&acc)[8][4], bf16x8 (&aF)[4][2], bf16x8 (&bF)[4][2]) {
  const int sw = l15 & 7;
#define RDF(buf, row, h) \
  __builtin_bit_cast(bf16x8, *(const u16x8*)&(buf)[(row) * 64 + ((((h) * 4 + quad) ^ sw) * 8)])
  // ---- P0: read A(mh0) + B(nt0,1) frags ----
#pragma unroll
  for (int mt = 0; mt < 4; ++mt) {
    const int row = wm * 128 + mt * 16 + l15;
    aF[mt][0] = RDF(sAc, row, 0);
    aF[mt][1] = RDF(sAc, row, 1);
  }
#pragma unroll
  for (int nt = 0; nt < 2; ++nt) {
    const int row = wn * 64 + nt * 16 + l15;
    bF[nt][0] = RDF(sBc, row, 0);
    bF[nt][1] = RDF(sBc, row, 1);
  }
  barx();
  __builtin_amdgcn_s_setprio(1);
#pragma unroll
  for (int h = 0; h < 2; ++h)
#pragma unroll
    for (int mt = 0; mt < 4; ++mt)
#pragma unroll
      for (int nt = 0; nt < 2; ++nt)
        acc[mt][nt] = __builtin_amdgcn_mfma_f32_16x16x32_bf16(aF[mt][h], bF[nt][h], acc[mt][nt], 0, 0, 0);
  __builtin_amdgcn_s_setprio(0);
  barx();
  // ---- P1: read B(nt2,3) frags ----
#pragma unroll
  for (int nt = 2; nt < 4; ++nt) {
    const int row = wn * 64 + nt * 16 + l15;
    bF[nt][0] = RDF(sBc, row, 0);
    bF[nt][1] = RDF(sBc, row, 1);
  }
  barx();
  __builtin_amdgcn_s_setprio(1);
#pragma unroll
  for (int h = 0; h < 2; ++h)
#pragma unroll
    for (int mt = 0; mt < 4; ++mt)
#pragma unroll
      for (int nt = 0; nt < 2; ++nt)
        acc[mt][2 + nt] = __builtin_amdgcn_mfma_f32_16x16x32_bf16(aF[mt][h], bF[2 + nt][h], acc[mt][2 + nt], 0, 0, 0);
  __builtin_amdgcn_s_setprio(0);
  barx();
  // ---- P2: read A(mh1) frags; stage B_{t+2} (B buffer fully consumed) ----
#pragma unroll
  for (int mt = 0; mt < 4; ++mt) {
    const int row = wm * 128 + (4 + mt) * 16 + l15;
    aF[mt][0] = RDF(sAc, row, 0);
    aF[mt][1] = RDF(sAc, row, 1);
  }
  if (STG) stage4(Bb, sBc, wv, srow, schunk, k2);
  barx();
  __builtin_amdgcn_s_setprio(1);
#pragma unroll
  for (int h = 0; h < 2; ++h)
#pragma unroll
    for (int mt = 0; mt < 4; ++mt)
#pragma unroll
      for (int nt = 0; nt < 2; ++nt)
        acc[4 + mt][nt] = __builtin_amdgcn_mfma_f32_16x16x32_bf16(aF[mt][h], bF[nt][h], acc[4 + mt][nt], 0, 0, 0);
  __builtin_amdgcn_s_setprio(0);
  barx();
  // ---- P3: stage A_{t+2} (A buffer fully consumed); wait tile t+1 complete ----
  if (STG) stage4(Ab, sAc, wv, srow, schunk, k2);
  waitv<BW>();
  barx();
  __builtin_amdgcn_s_setprio(1);
#pragma unroll
  for (int h = 0; h < 2; ++h)
#pragma unroll
    for (int mt = 0; mt < 4; ++mt)
#pragma unroll
      for (int nt = 0; nt < 2; ++nt)
        acc[4 + mt][2 + nt] = __builtin_amdgcn_mfma_f32_16x16x32_bf16(aF[mt][h], bF[2 + nt][h], acc[4 + mt][2 + nt], 0, 0, 0);
  __builtin_amdgcn_s_setprio(0);
  barx();
#undef RDF
}

__global__ __launch_bounds__(512, 2) void gemm8_k(
    const unsigned short* __restrict__ Abf, const unsigned short* __restrict__ Wt,
    const float* __restrict__ dp, const float* __restrict__ vw,
    float* __restrict__ sp) {
  __shared__ unsigned short sA[2][256 * 64];  // 64 KiB
  __shared__ unsigned short sB[2][256 * 64];  // 64 KiB
  const int tid = threadIdx.x;
  const int lane = tid & 63;
  const int wv = tid >> 6;            // 0..7
  const int wm = wv >> 2, wn = wv & 3;
  const int quad = lane >> 4;
  const int l15 = lane & 15;
  const int srow = lane >> 3;
  const int schunk = (lane & 7) ^ srow;

  // bijective XCD swizzle: the 4 bn-siblings of each bm land on consecutive
  // slots of ONE XCD (A-panel fetched once per XCD, L2-hit for the rest).
  const int f = blockIdx.x + (blockIdx.y << 2);  // 0..1023 as dispatched
  const int xcd = f & 7;
  const int c = f >> 3;                // 0..127 slot on this xcd
  const int bn = c & 3;                // 0..3
  const int bm = xcd + ((c >> 2) << 3);  // 0..255
  const int n0 = bn * 256;
  const int row0 = bm * 256;
  const int bidx = bm >> 3;            // batch index (2048 rows per batch)

  const unsigned short* Ab = Abf + (size_t)row0 * KDIM;
  const unsigned short* Bb = Wt + (size_t)n0 * KDIM;

  const f32x4 zz = {0.f, 0.f, 0.f, 0.f};
  f32x4 acc[8][4];
#pragma unroll
  for (int i = 0; i < 8; ++i)
#pragma unroll
    for (int j = 0; j < 4; ++j) acc[i][j] = zz;
  bf16x8 aF[4][2], bF[4][2];

  // prologue: stage tiles 0 and 1 (16 DMA); wait tile 0 (8 newest in flight).
  stage4(Bb, sB[0], wv, srow, schunk, 0);
  stage4(Ab, sA[0], wv, srow, schunk, 0);
  stage4(Bb, sB[1], wv, srow, schunk, 64);
  stage4(Ab, sA[1], wv, srow, schunk, 64);
  waitv<8>();
  barx();

  // tiles 0..13 stage t+2; 14,15 drain.
  for (int t = 0; t < 14; t += 2) {
    gtile2<true, 8>(sA[0], sB[0], Ab, Bb, (t + 2) * 64,
                    wm, wn, wv, quad, l15, srow, schunk, acc, aF, bF);
    gtile2<true, 8>(sA[1], sB[1], Ab, Bb, (t + 3) * 64,
                    wm, wn, wv, quad, l15, srow, schunk, acc, aF, bF);
  }
  gtile2<false, 0>(sA[0], sB[0], Ab, Bb, 0,
                   wm, wn, wv, quad, l15, srow, schunk, acc, aF, bF);
  gtile2<false, 0>(sA[1], sB[1], Ab, Bb, 0,
                   wm, wn, wv, quad, l15, srow, schunk, acc, aF, bF);

  // Epilogue: per-row tanh/v-dot partial over this block's 256 n-columns.
  float vv[4], dv[4];
#pragma unroll
  for (int nt = 0; nt < 4; ++nt) {
    const int n = n0 + wn * 64 + nt * 16 + l15;
    vv[nt] = vw[n];
    dv[nt] = dp[bidx * NDIM + n];  // bias already folded in
  }
  float* sRed = (float*)sA;  // reuse sA[0] as [4][256] scratch
#pragma unroll
  for (int mt = 0; mt < 8; ++mt) {
#pragma unroll
    for (int r = 0; r < 4; ++r) {
      float s = 0.f;
#pragma unroll
      for (int nt = 0; nt < 4; ++nt) {
        float x = acc[mt][nt][r] + dv[nt];
        x = fminf(fmaxf(x, -10.f), 10.f);
        const float e = __expf(2.f * x);
        s += (e - 1.f) * __builtin_amdgcn_rcpf(e + 1.f) * vv[nt];  // tanh
      }
      s += __shfl_xor(s, 1);
      s += __shfl_xor(s, 2);
      s += __shfl_xor(s, 4);
      s += __shfl_xor(s, 8);
      if (l15 == 0) sRed[wn * 256 + wm * 128 + mt * 16 + quad * 4 + r] = s;
    }
  }
  __syncthreads();
  if (tid < 256) {
    const float s4 = sRed[tid] + sRed[256 + tid] + sRed[512 + tid] + sRed[768 + tid];
    sp[(size_t)bn * MTOT + row0 + tid] = s4;
  }
}

// ---------------- fused softmax + context ----------------
// grid (8 echunks, 32 b), 256 threads. Each block recomputes the cheap softmax
// from sp partials (identical across ec -> consistent), keeps weights in LDS,
// then reduces context over all 2048 s for its 128-wide e-chunk.
__global__ __launch_bounds__(256) void sm_ctx_k(
    const float* __restrict__ sp, const int* __restrict__ mask,
    const unsigned short* __restrict__ Abf,
    float* __restrict__ attn, float* __restrict__ ctx) {
  __shared__ float a_s[SEQ];         // 8 KiB softmaxed weights
  __shared__ float red[16][16][8];   // 8 KiB context reduction
  __shared__ float redm[4], reds[4];
  const int ec = blockIdx.x;  // 0..7
  const int b = blockIdx.y;   // 0..31
  const int tid = threadIdx.x;
  const int w = tid >> 6;
  const int* mrow = mask + b * SEQ;
  float vals[8];
  float mx = -3.0e38f;
#pragma unroll
  for (int i = 0; i < 8; ++i) {
    const int s = tid + i * 256;
    float v = 0.f;
#pragma unroll
    for (int p = 0; p < 4; ++p) v += sp[(size_t)p * MTOT + b * SEQ + s];
    if (mrow[s] == 0) v = -1.0e9f;
    vals[i] = v;
    mx = fmaxf(mx, v);
  }
#pragma unroll
  for (int off = 1; off < 64; off <<= 1) mx = fmaxf(mx, __shfl_xor(mx, off));
  if ((tid & 63) == 0) redm[w] = mx;
  __syncthreads();
  mx = fmaxf(fmaxf(redm[0], redm[1]), fmaxf(redm[2], redm[3]));
  float sum = 0.f;
#pragma unroll
  for (int i = 0; i < 8; ++i) {
    vals[i] = __expf(vals[i] - mx);
    sum += vals[i];
  }
#pragma unroll
  for (int off = 1; off < 64; off <<= 1) sum += __shfl_xor(sum, off);
  if ((tid & 63) == 0) reds[w] = sum;
  __syncthreads();
  sum = reds[0] + reds[1] + reds[2] + reds[3];
  const float inv = 1.0f / sum;
#pragma unroll
  for (int i = 0; i < 8; ++i) {
    const float av = vals[i] * inv;
    a_s[tid + i * 256] = av;
    if (ec == 0) attn[b * SEQ + tid + i * 256] = av;
  }
  __syncthreads();
  // context: thread (sg, es) accumulates 8 e's over s = sg, sg+16, ...
  const int sg = tid >> 4, es = tid & 15;
  const int e0 = ec * 128 + es * 8;
  const unsigned short* base = Abf + (size_t)(b * SEQ) * ENCD + e0;
  float acc[8] = {0.f, 0.f, 0.f, 0.f, 0.f, 0.f, 0.f, 0.f};
#pragma unroll 4
  for (int k = 0; k < 128; ++k) {
    const int s = sg + k * 16;
    const float wgt = a_s[s];
    const u16x8 v = *(const u16x8*)(base + (size_t)s * ENCD);
#pragma unroll
    for (int j = 0; j < 8; ++j) acc[j] = fmaf(wgt, bf2f(v[j]), acc[j]);
  }
#pragma unroll
  for (int j = 0; j < 8; ++j) red[sg][es][j] = acc[j];
  __syncthreads();
  if (tid < 128) {
    const int es2 = tid >> 3, j = tid & 7;
    float ssum = 0.f;
#pragma unroll
    for (int g = 0; g < 16; ++g) ssum += red[g][es2][j];
    ctx[b * ENCD + ec * 128 + es2 * 8 + j] = ssum;
  }
}

// ================= Path B/C fallback kernels (round-3 proven) =================
__global__ void dec_proj_k2(const float* __restrict__ dec, const float* __restrict__ W,
                            float* __restrict__ dp) {
  const int idx = blockIdx.x * 256 + threadIdx.x;
  const int kc = blockIdx.y;
  const int b = idx >> 10;
  const int n = idx & 1023;
  const float* d = dec + b * DECD + kc * 128;
  const float* w = W + (long)(kc * 128) * NDIM + n;
  float acc = 0.f;
#pragma unroll 8
  for (int k = 0; k < 128; ++k) acc = fmaf(d[k], w[(long)k * NDIM], acc);
  atomicAdd(&dp[idx], acc);
}

__global__ __launch_bounds__(256, 3) void gemm_scores_bf16(
    const unsigned short* __restrict__ Abf, const unsigned short* __restrict__ Wt,
    const float* __restrict__ dp, const float* __restrict__ bias,
    const float* __restrict__ vw, float* __restrict__ scores) {
  __shared__ unsigned short sA[128 * 64];
  __shared__ unsigned short sB[128 * 64];
  const int tid = threadIdx.x;
  const int lane = tid & 63;
  const int wave = tid >> 6;
  const int wm = wave >> 1, wn = wave & 1;
  const int quad = lane >> 4;
  const int l15 = lane & 15;
  const int bn = blockIdx.x, bm = blockIdx.y;
  const int n0 = bn * 128, row0 = bm * 128, bidx = bm >> 4;
  const int srow = lane >> 3;
  const int schunk = (lane & 7) ^ srow;
  const f32x4 zz = {0.f, 0.f, 0.f, 0.f};
  f32x4 acc[4][4];
#pragma unroll
  for (int i = 0; i < 4; ++i)
#pragma unroll
    for (int j = 0; j < 4; ++j) acc[i][j] = zz;
  for (int kt = 0; kt < 16; ++kt) {
    const int k0 = kt * 64;
    __syncthreads();
#pragma unroll
    for (int i = 0; i < 4; ++i) {
      const int r = wave * 32 + i * 8 + srow;
      async_lds16(Abf + (size_t)(row0 + r) * KDIM + k0 + schunk * 8,
                  &sA[(wave * 32 + i * 8) * 64]);
      async_lds16(Wt + (size_t)(n0 + r) * KDIM + k0 + schunk * 8,
                  &sB[(wave * 32 + i * 8) * 64]);
    }
    __syncthreads();
#pragma unroll
    for (int h = 0; h < 2; ++h) {
      bf16x8 af[4], bf[4];
      const int slot = ((h * 4 + quad) ^ (l15 & 7)) * 8;
#pragma unroll
      for (int t = 0; t < 4; ++t) {
        af[t] = __builtin_bit_cast(bf16x8, *(const u16x8*)&sA[(wm * 64 + t * 16 + l15) * 64 + slot]);
        bf[t] = __builtin_bit_cast(bf16x8, *(const u16x8*)&sB[(wn * 64 + t * 16 + l15) * 64 + slot]);
      }
#pragma unroll
      for (int mt = 0; mt < 4; ++mt)
#pragma unroll
        for (int nt = 0; nt < 4; ++nt)
          acc[mt][nt] = __builtin_amdgcn_mfma_f32_16x16x32_bf16(
              af[mt], bf[nt], acc[mt][nt], 0, 0, 0);
    }
  }
  float vv[4], dv[4];
#pragma unroll
  for (int nt = 0; nt < 4; ++nt) {
    const int n = n0 + wn * 64 + nt * 16 + l15;
    vv[nt] = vw[n];
    dv[nt] = dp[bidx * NDIM + n] + bias[n];
  }
#pragma unroll
  for (int mt = 0; mt < 4; ++mt) {
#pragma unroll
    for (int r = 0; r < 4; ++r) {
      float s = 0.f;
#pragma unroll
      for (int nt = 0; nt < 4; ++nt) {
        float x = acc[mt][nt][r] + dv[nt];
        x = fminf(fmaxf(x, -10.f), 10.f);
        const float e = __expf(2.f * x);
        s += (e - 1.f) * __builtin_amdgcn_rcpf(e + 1.f) * vv[nt];
      }
      s += __shfl_xor(s, 1);
      s += __shfl_xor(s, 2);
      s += __shfl_xor(s, 4);
      s += __shfl_xor(s, 8);
      if (l15 == 0) atomicAdd(&scores[row0 + wm * 64 + mt * 16 + quad * 4 + r], s);
    }
  }
}

__global__ __launch_bounds__(256, 2) void gemm_scores_f32(
    const float* __restrict__ Ag, const unsigned short* __restrict__ Wt,
    const float* __restrict__ dp, const float* __restrict__ bias,
    const float* __restrict__ vw, float* __restrict__ scores) {
  __shared__ unsigned short sA[128 * 64];
  __shared__ unsigned short sB[128 * 64];
  const int tid = threadIdx.x;
  const int lane = tid & 63;
  const int wave = tid >> 6;
  const int wm = wave >> 1, wn = wave & 1;
  const int quad = lane >> 4;
  const int l15 = lane & 15;
  const int bn = blockIdx.x, bm = blockIdx.y;
  const int n0 = bn * 128, row0 = bm * 128, bidx = bm >> 4;
  const int sr = tid >> 3, sc = tid & 7;
  const f32x4 zz = {0.f, 0.f, 0.f, 0.f};
  f32x4 acc[4][4];
#pragma unroll
  for (int i = 0; i < 4; ++i)
#pragma unroll
    for (int j = 0; j < 4; ++j) acc[i][j] = zz;
  for (int kt = 0; kt < 16; ++kt) {
    const int k0 = kt * 64;
    __syncthreads();
#pragma unroll
    for (int j = 0; j < 4; ++j) {
      const int r = sr + 32 * j;
      const int c = sc ^ (r & 7);
      const float* src = Ag + (long)(row0 + r) * KDIM + (k0 + c * 8);
      f32x4 f0 = *(const f32x4*)src;
      f32x4 f1 = *(const f32x4*)(src + 4);
      u16x8 v;
      v[0] = f2bf(f0[0]); v[1] = f2bf(f0[1]); v[2] = f2bf(f0[2]); v[3] = f2bf(f0[3]);
      v[4] = f2bf(f1[0]); v[5] = f2bf(f1[1]); v[6] = f2bf(f1[2]); v[7] = f2bf(f1[3]);
      *(u16x8*)&sA[r * 64 + sc * 8] = v;
      *(u16x8*)&sB[r * 64 + sc * 8] = *(const u16x8*)(Wt + (long)(n0 + r) * KDIM + (k0 + c * 8));
    }
    __syncthreads();
#pragma unroll
    for (int h = 0; h < 2; ++h) {
      const int cs = ((h * 4 + quad) ^ (lane & 7)) * 8;
      bf16x8 af[4], bf[4];
#pragma unroll
      for (int t = 0; t < 4; ++t) {
        af[t] = __builtin_bit_cast(bf16x8, *(const u16x8*)&sA[(wm * 64 + t * 16 + l15) * 64 + cs]);
        bf[t] = __builtin_bit_cast(bf16x8, *(const u16x8*)&sB[(wn * 64 + t * 16 + l15) * 64 + cs]);
      }
#pragma unroll
      for (int mt = 0; mt < 4; ++mt)
#pragma unroll
        for (int nt = 0; nt < 4; ++nt)
          acc[mt][nt] = __builtin_amdgcn_mfma_f32_16x16x32_bf16(
              af[mt], bf[nt], acc[mt][nt], 0, 0, 0);
    }
  }
  float vv[4], dv[4];
#pragma unroll
  for (int nt = 0; nt < 4; ++nt) {
    const int n = n0 + wn * 64 + nt * 16 + l15;
    vv[nt] = vw[n];
    dv[nt] = dp[bidx * NDIM + n] + bias[n];
  }
#pragma unroll
  for (int mt = 0; mt < 4; ++mt) {
#pragma unroll
    for (int r = 0; r < 4; ++r) {
      float s = 0.f;
#pragma unroll
      for (int nt = 0; nt < 4; ++nt) {
        float x = acc[mt][nt][r] + dv[nt];
        x = fminf(fmaxf(x, -10.f), 10.f);
        const float e = __expf(2.f * x);
        s += (e - 1.f) * __builtin_amdgcn_rcpf(e + 1.f) * vv[nt];
      }
      s += __shfl_xor(s, 1);
      s += __shfl_xor(s, 2);
      s += __shfl_xor(s, 4);
      s += __shfl_xor(s, 8);
      if (l15 == 0) atomicAdd(&scores[row0 + wm * 64 + mt * 16 + quad * 4 + r], s);
    }
  }
}

__global__ void softmax_k(float* __restrict__ sc, const int* __restrict__ mask) {
  const int b = blockIdx.x;
  const int tid = threadIdx.x;
  const int w = tid >> 6;
  __shared__ float redm[4], reds[4];
  float* row = sc + b * SEQ;
  const int* mrow = mask + b * SEQ;
  float vals[8];
  float mx = -3.0e38f;
#pragma unroll
  for (int i = 0; i < 8; ++i) {
    const int s = tid + i * 256;
    float v = row[s];
    if (mrow[s] == 0) v = -1.0e9f;
    vals[i] = v;
    mx = fmaxf(mx, v);
  }
#pragma unroll
  for (int off = 1; off < 64; off <<= 1) mx = fmaxf(mx, __shfl_xor(mx, off));
  if ((tid & 63) == 0) redm[w] = mx;
  __syncthreads();
  mx = fmaxf(fmaxf(redm[0], redm[1]), fmaxf(redm[2], redm[3]));
  float sum = 0.f;
#pragma unroll
  for (int i = 0; i < 8; ++i) {
    vals[i] = __expf(vals[i] - mx);
    sum += vals[i];
  }
#pragma unroll
  for (int off = 1; off < 64; off <<= 1) sum += __shfl_xor(sum, off);
  if ((tid & 63) == 0) reds[w] = sum;
  __syncthreads();
  sum = reds[0] + reds[1] + reds[2] + reds[3];
  const float inv = 1.0f / sum;
#pragma unroll
  for (int i = 0; i < 8; ++i) row[tid + i * 256] = vals[i] * inv;
}

__global__ void context_k(const float* __restrict__ attn, const float* __restrict__ enc,
                          float* __restrict__ ctx) {
  const int b = blockIdx.y;
  const int s0 = blockIdx.x * 32;
  const int e = threadIdx.x * 4;
  const float* arow = attn + b * SEQ + s0;
  const float* ebase = enc + (long)(b * SEQ + s0) * ENCD + e;
  f32x4 acc = {0.f, 0.f, 0.f, 0.f};
#pragma unroll 8
  for (int s = 0; s < 32; ++s) {
    const float w = arow[s];
    const f32x4 v = *(const f32x4*)(ebase + (long)s * ENCD);
    acc += w * v;
  }
  float* dst = ctx + b * ENCD + e;
  atomicAdd(dst + 0, acc[0]);
  atomicAdd(dst + 1, acc[1]);
  atomicAdd(dst + 2, acc[2]);
  atomicAdd(dst + 3, acc[3]);
}

extern "C" void kernel_launch(void* const* d_in, const int* in_sizes, int n_in,
                              void* d_out, int out_size, void* d_ws, size_t ws_size,
                              hipStream_t stream) {
  (void)in_sizes; (void)n_in; (void)out_size;
  const float* dec  = (const float*)d_in[0];
  const float* enc  = (const float*)d_in[1];
  const int*   mask = (const int*)d_in[2];
  const float* W    = (const float*)d_in[3];
  const float* bias = (const float*)d_in[4];
  const float* vw   = (const float*)d_in[5];

  float* ctx  = (float*)d_out;                 // context region (also dp parking)
  float* attn = (float*)d_out + BATCH * ENCD;  // attn region (scores in-place for B/C)
  unsigned short* Wt  = (unsigned short*)d_ws;                         // 2 MiB
  unsigned short* Abf = (unsigned short*)((char*)d_ws + (2ull << 20)); // 128 MiB
  float* shared = (float*)((char*)d_ws + (130ull << 20));              // 2 MiB multi-use

  const size_t needA = (132ull << 20);
  const size_t needB = (2ull << 20) + ((size_t)MTOT * KDIM * 2);

  if (ws_size >= needA) {
    // 3 dispatches total.
    prep_k<<<384 + 32768, 256, 0, stream>>>(dec, enc, W, bias, ctx, Wt, Abf);
    // score partials sp[4][65536] -> shared (1 MiB)
    gemm8_k<<<dim3(4, 256), 512, 0, stream>>>(Abf, Wt, ctx, vw, shared);
    sm_ctx_k<<<dim3(8, 32), 256, 0, stream>>>(shared, mask, Abf, attn, ctx);
  } else if (ws_size >= needB) {
    wt_k<<<dim3(16, 16), 256, 0, stream>>>(W, Wt);
    hipMemsetAsync(attn, 0, (size_t)MTOT * sizeof(float), stream);
    hipMemsetAsync(ctx, 0, (size_t)(BATCH * NDIM) * sizeof(float), stream);
    dec_proj_k2<<<dim3(128, 8), 256, 0, stream>>>(dec, W, ctx);
    conv_bf16_k<<<32768, 256, 0, stream>>>(enc, Abf);
    gemm_scores_bf16<<<dim3(8, 512), 256, 0, stream>>>(Abf, Wt, ctx, bias, vw, attn);
    softmax_k<<<32, 256, 0, stream>>>(attn, mask);
    hipMemsetAsync(ctx, 0, (size_t)(BATCH * ENCD) * sizeof(float), stream);
    context_k<<<dim3(64, 32), 256, 0, stream>>>(attn, enc, ctx);
  } else {
    wt_k<<<dim3(16, 16), 256, 0, stream>>>(W, Wt);
    hipMemsetAsync(attn, 0, (size_t)MTOT * sizeof(float), stream);
    hipMemsetAsync(ctx, 0, (size_t)(BATCH * NDIM) * sizeof(float), stream);
    dec_proj_k2<<<dim3(128, 8), 256, 0, stream>>>(dec, W, ctx);
    gemm_scores_f32<<<dim3(8, 512), 256, 0, stream>>>(enc, Wt, ctx, bias, vw, attn);
    softmax_k<<<32, 256, 0, stream>>>(attn, mask);
    hipMemsetAsync(ctx, 0, (size_t)(BATCH * ENCD) * sizeof(float), stream);
    context_k<<<dim3(64, 32), 256, 0, stream>>>(attn, enc, ctx);
  }
}